// Round 2
// baseline (431.142 us; speedup 1.0000x reference)
//
#include <hip/hip_runtime.h>
#include <hip/hip_bf16.h>
#include <stdint.h>

#define VOCAB 10000
#define XDIM 128
#define HID 256
#define BATCH 128
#define SEQ 50
#define ROWS (BATCH * SEQ) /* 6400 */

#define BM 128
#define BN 128
#define BK 64
#define NTM 50 /* 6400/128 */
#define NTN 79 /* ceil(10000/128) */

typedef __bf16 bf16x8 __attribute__((ext_vector_type(8)));
typedef float f32x4 __attribute__((ext_vector_type(4)));

__device__ __forceinline__ uint16_t f2bf(float f) {
    union { float f; uint32_t i; } v;
    v.f = f;
    uint32_t x = v.i;
    // round-to-nearest-even
    return (uint16_t)((x + 0x7fffu + ((x >> 16) & 1u)) >> 16);
}

// ---------------------------------------------------------------------------
// K0: cast W_aff (fp32) -> bf16 into workspace. 2.56M elems, 8/thread.
// ---------------------------------------------------------------------------
__global__ __launch_bounds__(256) void k0_cast(
    const float* __restrict__ src, uint16_t* __restrict__ dst) {
    const int i = (blockIdx.x * 256 + threadIdx.x) * 8;
    float4 a = *(const float4*)(src + i);
    float4 b = *(const float4*)(src + i + 4);
    uint16_t t[8];
    t[0] = f2bf(a.x); t[1] = f2bf(a.y); t[2] = f2bf(a.z); t[3] = f2bf(a.w);
    t[4] = f2bf(b.x); t[5] = f2bf(b.y); t[6] = f2bf(b.z); t[7] = f2bf(b.w);
    *(uint4*)(dst + i) = *(const uint4*)t;
}

// ---------------------------------------------------------------------------
// K1: xin[r][j] = dot(emb[x[r]], W_ih[j]) + b_ih[j] + b_hh[j]   (fp32)
// 8 rows per block; emb rows staged in LDS; W_ih row j in 128 registers.
// ---------------------------------------------------------------------------
__global__ __launch_bounds__(256, 2) void k1_xin(
    const int* __restrict__ x, const float* __restrict__ emb,
    const float* __restrict__ Wih, const float* __restrict__ bih,
    const float* __restrict__ bhh, float* __restrict__ xin) {
    __shared__ __align__(16) float es[8][XDIM];
    const int r0 = blockIdx.x * 8;
    const int tid = threadIdx.x;

    {   // stage 8 emb rows: 256 threads x 4 floats = 1024 floats
        const int row = tid >> 5, c = tid & 31;
        const int tok = x[r0 + row];
        *(float4*)&es[row][c * 4] = *(const float4*)(emb + tok * XDIM + c * 4);
    }
    __syncthreads();

    const int j = tid;
    float wf[XDIM];
    const float4* wrow = (const float4*)(Wih + j * XDIM);
#pragma unroll
    for (int c = 0; c < 32; ++c) *(float4*)&wf[c * 4] = wrow[c];
    const float bias = bih[j] + bhh[j];

    float acc[8];
#pragma unroll
    for (int r = 0; r < 8; ++r) acc[r] = bias;
#pragma unroll
    for (int k4 = 0; k4 < 32; ++k4) {
#pragma unroll
        for (int r = 0; r < 8; ++r) {
            float4 e = *(const float4*)&es[r][k4 * 4];
            acc[r] += e.x * wf[k4 * 4 + 0] + e.y * wf[k4 * 4 + 1] +
                      e.z * wf[k4 * 4 + 2] + e.w * wf[k4 * 4 + 3];
        }
    }
#pragma unroll
    for (int r = 0; r < 8; ++r) xin[(r0 + r) * HID + j] = acc[r];
}

// ---------------------------------------------------------------------------
// K2: recurrence, exact fp32. Block b = batch b. Thread j owns h[j]; W_hh
// row j in 256 registers; h in LDS (broadcast float4 reads, conflict-free).
// Emits hs as bf16 for the MFMA GEMM.
// ---------------------------------------------------------------------------
__global__ __launch_bounds__(256, 1) void k2_rnn(
    const float* __restrict__ xin, const float* __restrict__ Whh,
    uint16_t* __restrict__ hs) {
    __shared__ __align__(16) float hb[HID];
    const int b = blockIdx.x, j = threadIdx.x;

    float wh[HID];
    const float4* wrow = (const float4*)(Whh + j * HID);
#pragma unroll
    for (int c = 0; c < 64; ++c) *(float4*)&wh[c * 4] = wrow[c];

    hb[j] = 0.0f;
    __syncthreads();

    const float* xr = xin + b * SEQ * HID;
    uint16_t* hr = hs + b * SEQ * HID;

    for (int t = 0; t < SEQ; ++t) {
        float acc = xr[t * HID + j];
        const float4* h4 = (const float4*)hb;
        float a4[4] = {0.f, 0.f, 0.f, 0.f};
#pragma unroll
        for (int c = 0; c < 64; ++c) {
            float4 v = h4[c];
            a4[c & 3] += v.x * wh[4 * c + 0] + v.y * wh[4 * c + 1] +
                         v.z * wh[4 * c + 2] + v.w * wh[4 * c + 3];
        }
        acc += (a4[0] + a4[1]) + (a4[2] + a4[3]);
        float hn = tanhf(acc);
        __syncthreads();              // all reads of hb done
        hb[j] = hn;
        hr[t * HID + j] = f2bf(hn);
        __syncthreads();              // writes visible before next reads
    }
}

// ---------------------------------------------------------------------------
// K3: ys[m][n] = sum_k hs[m][k] * W_aff[n][k] + b_aff[n]  (fp32 out)
// 128x128 tile, BK=64, global_load_lds(16B) staging, mfma 16x16x32 bf16.
// A = hs (bf16 ws), B = W_aff (bf16 ws), bias fp32, out fp32.
// ---------------------------------------------------------------------------
__global__ __launch_bounds__(256, 2) void k3_gemm(
    const uint16_t* __restrict__ A,   // hs  [6400][256] bf16
    const uint16_t* __restrict__ Bw,  // W_aff [10000][256] bf16
    const float* __restrict__ baff,   // [10000] fp32
    float* __restrict__ out) {
    __shared__ __align__(16) uint16_t As[BM * BK];
    __shared__ __align__(16) uint16_t Bs[BN * BK];

    const int bid = blockIdx.x;
    const int bm = bid % NTM, bn = bid / NTM;
    const int m0 = bm * BM, n0 = bn * BN;
    const int tid = threadIdx.x;
    const int wv = tid >> 6, ln = tid & 63;
    const int wm = wv & 1, wn = wv >> 1;

    f32x4 acc[4][4];
#pragma unroll
    for (int i = 0; i < 4; ++i)
#pragma unroll
        for (int j = 0; j < 4; ++j) acc[i][j] = (f32x4)0.0f;

    const int lrow = ln >> 3;        // 0..7 within 8-row chunk
    const int lcol = (ln & 7) * 8;   // bf16 col offset (16B granules)

    for (int kt = 0; kt < 4; ++kt) {
        const int k0 = kt * BK;
#pragma unroll
        for (int i = 0; i < 4; ++i) {
            const int ci = wv * 4 + i;
            const uint16_t* g = A + (size_t)(m0 + ci * 8 + lrow) * HID + k0 + lcol;
            __builtin_amdgcn_global_load_lds(
                (const __attribute__((address_space(1))) void*)g,
                (__attribute__((address_space(3))) void*)(As + ci * 512), 16, 0, 0);
        }
#pragma unroll
        for (int i = 0; i < 4; ++i) {
            const int ci = wv * 4 + i;
            int n = n0 + ci * 8 + lrow;
            if (n > VOCAB - 1) n = VOCAB - 1;   // clamp OOB rows; stores guarded
            const uint16_t* g = Bw + (size_t)n * HID + k0 + lcol;
            __builtin_amdgcn_global_load_lds(
                (const __attribute__((address_space(1))) void*)g,
                (__attribute__((address_space(3))) void*)(Bs + ci * 512), 16, 0, 0);
        }
        __syncthreads();  // vmcnt(0) drain + barrier

#pragma unroll
        for (int kk = 0; kk < 2; ++kk) {
            const int krd = kk * 32 + (ln >> 4) * 8;
            bf16x8 af[4], bf[4];
#pragma unroll
            for (int tm = 0; tm < 4; ++tm)
                af[tm] = *(const bf16x8*)&As[(wm * 64 + tm * 16 + (ln & 15)) * BK + krd];
#pragma unroll
            for (int tn = 0; tn < 4; ++tn)
                bf[tn] = *(const bf16x8*)&Bs[(wn * 64 + tn * 16 + (ln & 15)) * BK + krd];
#pragma unroll
            for (int tm = 0; tm < 4; ++tm)
#pragma unroll
                for (int tn = 0; tn < 4; ++tn)
                    acc[tm][tn] = __builtin_amdgcn_mfma_f32_16x16x32_bf16(
                        af[tm], bf[tn], acc[tm][tn], 0, 0, 0);
        }
        __syncthreads();
    }

    // epilogue: C layout col = lane&15, row = (lane>>4)*4 + reg
    float bias[4];
#pragma unroll
    for (int tn = 0; tn < 4; ++tn) {
        int n = n0 + wn * 64 + tn * 16 + (ln & 15);
        bias[tn] = baff[n > VOCAB - 1 ? VOCAB - 1 : n];
    }
#pragma unroll
    for (int tm = 0; tm < 4; ++tm) {
        const int mbase = m0 + wm * 64 + tm * 16 + (ln >> 4) * 4;
#pragma unroll
        for (int r = 0; r < 4; ++r) {
            float* orow = out + (size_t)(mbase + r) * VOCAB;
#pragma unroll
            for (int tn = 0; tn < 4; ++tn) {
                int n = n0 + wn * 64 + tn * 16 + (ln & 15);
                if (n < VOCAB) orow[n] = acc[tm][tn][r] + bias[tn];
            }
        }
    }
}

extern "C" void kernel_launch(void* const* d_in, const int* in_sizes, int n_in,
                              void* d_out, int out_size, void* d_ws, size_t ws_size,
                              hipStream_t stream) {
    const int* x = (const int*)d_in[0];
    const float* emb = (const float*)d_in[1];
    const float* Wih = (const float*)d_in[2];
    const float* Whh = (const float*)d_in[3];
    const float* bih = (const float*)d_in[4];
    const float* bhh = (const float*)d_in[5];
    const float* Waff = (const float*)d_in[6];
    const float* baff = (const float*)d_in[7];

    // workspace layout (all 16B-aligned):
    float* xin = (float*)d_ws;                                  // 6400*256 f32
    uint16_t* hsb = (uint16_t*)((char*)d_ws + (size_t)ROWS * HID * 4);   // bf16
    uint16_t* Wb = hsb + (size_t)ROWS * HID;                    // 10000*256 bf16
    float* out = (float*)d_out;

    k0_cast<<<(VOCAB * HID) / (256 * 8), 256, 0, stream>>>(Waff, Wb);
    k1_xin<<<ROWS / 8, 256, 0, stream>>>(x, emb, Wih, bih, bhh, xin);
    k2_rnn<<<BATCH, 256, 0, stream>>>(xin, Whh, hsb);
    k3_gemm<<<NTM * NTN, 256, 0, stream>>>(hsb, Wb, baff, out);
}

// Round 3
// 382.698 us; speedup vs baseline: 1.1266x; 1.1266x over previous
//
#include <hip/hip_runtime.h>
#include <hip/hip_bf16.h>
#include <stdint.h>

#define VOCAB 10000
#define XDIM 128
#define HID 256
#define BATCH 128
#define SEQ 50
#define ROWS (BATCH * SEQ) /* 6400 */

// K3 tiling
#define BM 128
#define BN 256
#define BK 64
#define NTM 50 /* 6400/128 */
#define NTN 40 /* ceil(10000/256) */

typedef __bf16 bf16x8 __attribute__((ext_vector_type(8)));
typedef float f32x4 __attribute__((ext_vector_type(4)));

__device__ __forceinline__ uint16_t f2bf(float f) {
    union { float f; uint32_t i; } v;
    v.f = f;
    uint32_t x = v.i;
    return (uint16_t)((x + 0x7fffu + ((x >> 16) & 1u)) >> 16); // RNE
}

// ---------------------------------------------------------------------------
// K0: cast W_aff (fp32) -> bf16 into workspace. 2.56M elems, 8/thread.
// ---------------------------------------------------------------------------
__global__ __launch_bounds__(256) void k0_cast(
    const float* __restrict__ src, uint16_t* __restrict__ dst) {
    const int i = (blockIdx.x * 256 + threadIdx.x) * 8;
    float4 a = *(const float4*)(src + i);
    float4 b = *(const float4*)(src + i + 4);
    uint16_t t[8];
    t[0] = f2bf(a.x); t[1] = f2bf(a.y); t[2] = f2bf(a.z); t[3] = f2bf(a.w);
    t[4] = f2bf(b.x); t[5] = f2bf(b.y); t[6] = f2bf(b.z); t[7] = f2bf(b.w);
    *(uint4*)(dst + i) = *(const uint4*)t;
}

// ---------------------------------------------------------------------------
// K1: xin[r][j] = dot(emb[x[r]], W_ih[j]) + b_ih[j] + b_hh[j]   (fp32)
// 8 rows/block; emb rows in LDS (broadcast reads); W_ih row j in 128 regs.
// ---------------------------------------------------------------------------
__global__ __launch_bounds__(256, 2) void k1_xin(
    const int* __restrict__ x, const float* __restrict__ emb,
    const float* __restrict__ Wih, const float* __restrict__ bih,
    const float* __restrict__ bhh, float* __restrict__ xin) {
    __shared__ __align__(16) float es[8][XDIM];
    const int r0 = blockIdx.x * 8;
    const int tid = threadIdx.x;

    {   // stage 8 emb rows: 256 threads x 4 floats
        const int row = tid >> 5, c = tid & 31;
        const int tok = x[r0 + row];
        *(float4*)&es[row][c * 4] = *(const float4*)(emb + tok * XDIM + c * 4);
    }
    __syncthreads();

    const int j = tid;
    float wf[XDIM];
    const float4* wrow = (const float4*)(Wih + j * XDIM);
#pragma unroll
    for (int c = 0; c < 32; ++c) *(float4*)&wf[c * 4] = wrow[c];
    const float bias = bih[j] + bhh[j];

    float acc[8];
#pragma unroll
    for (int r = 0; r < 8; ++r) acc[r] = bias;
#pragma unroll
    for (int k4 = 0; k4 < 32; ++k4) {
#pragma unroll
        for (int r = 0; r < 8; ++r) {
            float4 e = *(const float4*)&es[r][k4 * 4];
            acc[r] += e.x * wf[k4 * 4 + 0] + e.y * wf[k4 * 4 + 1] +
                      e.z * wf[k4 * 4 + 2] + e.w * wf[k4 * 4 + 3];
        }
    }
#pragma unroll
    for (int r = 0; r < 8; ++r) xin[(r0 + r) * HID + j] = acc[r];
}

// ---------------------------------------------------------------------------
// K2v3: recurrence, split-K. 512 threads: tid = half*256 + j. Thread holds
// W_hh[j][half*128..+128) in 128 VGPRs (no AGPR/spill risk). h in LDS
// (broadcast float4 reads, conflict-free); halves combine via ps[] in LDS.
// Emits hs as bf16 for the MFMA GEMM. Exact fp32 recurrence.
// ---------------------------------------------------------------------------
__global__ __launch_bounds__(512, 2) void k2_rnn(
    const float* __restrict__ xin, const float* __restrict__ Whh,
    uint16_t* __restrict__ hs) {
    __shared__ __align__(16) float hb[HID];
    __shared__ float ps[HID];
    const int b = blockIdx.x;
    const int j = threadIdx.x & 255;
    const int half = threadIdx.x >> 8;

    float wh[128];
    const float4* wrow = (const float4*)(Whh + j * HID + half * 128);
#pragma unroll
    for (int c = 0; c < 32; ++c) *(float4*)&wh[c * 4] = wrow[c];

    if (threadIdx.x < HID) hb[threadIdx.x] = 0.0f;
    __syncthreads();

    const float* xr = xin + b * SEQ * HID;
    uint16_t* hr = hs + b * SEQ * HID;

    for (int t = 0; t < SEQ; ++t) {
        const float xv = xr[t * HID + j];   // only half 0 uses; overlap latency
        const float4* h4 = (const float4*)(hb + half * 128);
        float a0 = 0.f, a1 = 0.f, a2 = 0.f, a3 = 0.f;
#pragma unroll
        for (int c = 0; c < 32; ++c) {
            float4 v = h4[c];
            a0 += v.x * wh[c * 4 + 0];
            a1 += v.y * wh[c * 4 + 1];
            a2 += v.z * wh[c * 4 + 2];
            a3 += v.w * wh[c * 4 + 3];
        }
        const float part = (a0 + a1) + (a2 + a3);
        if (half) ps[j] = part;
        __syncthreads();                    // ps visible; all hb reads done
        if (!half) {
            const float hn = tanhf(part + ps[j] + xv);
            hb[j] = hn;
            hr[t * HID + j] = f2bf(hn);
        }
        __syncthreads();                    // new hb visible
    }
}

// ---------------------------------------------------------------------------
// K3v2: ys[m][n] = sum_k hs[m][k]*W_aff[n][k] + b_aff[n]  (fp32 out)
// 128x256 tile, BK=64. XOR-swizzled LDS: row R's k-granule gk (8 bf16 = 16B)
// lives at slot gk^(R&7) -> fragment ds_read_b128 spreads over all 8 bank
// groups (2-way aliasing = free). Staging permutes the GLOBAL source granule
// per lane (LDS dest of global_load_lds is fixed base+lane*16).
// ---------------------------------------------------------------------------
__global__ __launch_bounds__(256, 2) void k3_gemm(
    const uint16_t* __restrict__ A,   // hs  [6400][256] bf16
    const uint16_t* __restrict__ Bw,  // W_aff [10000][256] bf16
    const float* __restrict__ baff,   // [10000] fp32
    float* __restrict__ out) {
    __shared__ __align__(16) uint16_t As[BM * BK];   // 16 KB
    __shared__ __align__(16) uint16_t Bs[BN * BK];   // 32 KB

    const int bid = blockIdx.x;
    const int bm = bid % NTM, bn = bid / NTM;
    const int m0 = bm * BM, n0 = bn * BN;
    const int tid = threadIdx.x;
    const int wv = tid >> 6, ln = tid & 63;
    const int wm = wv & 1, wn = wv >> 1;   // 2x2 wave grid: 64 x 128 per wave
    const int quad = ln >> 4, l15 = ln & 15;

    f32x4 acc[4][8];
#pragma unroll
    for (int i = 0; i < 4; ++i)
#pragma unroll
        for (int jj = 0; jj < 8; ++jj) acc[i][jj] = (f32x4)0.0f;

    const int lrow = ln >> 3;               // 0..7 row within 8-row chunk
    const int gsw = ((ln & 7) ^ lrow) * 8;  // swizzled source granule (elems)

    for (int kt = 0; kt < 4; ++kt) {
        const int k0 = kt * BK;
        // stage A: 16 chunks of 1 KiB; wave wv does 4
#pragma unroll
        for (int i = 0; i < 4; ++i) {
            const int ci = wv * 4 + i;
            const uint16_t* g = A + (size_t)(m0 + ci * 8 + lrow) * HID + k0 + gsw;
            __builtin_amdgcn_global_load_lds(
                (const __attribute__((address_space(1))) void*)g,
                (__attribute__((address_space(3))) void*)(As + ci * 512), 16, 0, 0);
        }
        // stage B: 32 chunks; wave wv does 8 (clamp OOB rows; stores guarded)
#pragma unroll
        for (int i = 0; i < 8; ++i) {
            const int ci = wv * 8 + i;
            int n = n0 + ci * 8 + lrow;
            if (n > VOCAB - 1) n = VOCAB - 1;
            const uint16_t* g = Bw + (size_t)n * HID + k0 + gsw;
            __builtin_amdgcn_global_load_lds(
                (const __attribute__((address_space(1))) void*)g,
                (__attribute__((address_space(3))) void*)(Bs + ci * 512), 16, 0, 0);
        }
        __syncthreads();  // vmcnt(0) drain + barrier

#pragma unroll
        for (int kk = 0; kk < 2; ++kk) {
            const int gk = kk * 4 + quad;   // k-granule index for this lane
            bf16x8 af[4], bf[8];
#pragma unroll
            for (int tm = 0; tm < 4; ++tm) {
                const int R = wm * 64 + tm * 16 + l15;
                af[tm] = *(const bf16x8*)&As[R * 64 + ((gk ^ (R & 7)) * 8)];
            }
#pragma unroll
            for (int tn = 0; tn < 8; ++tn) {
                const int R = wn * 128 + tn * 16 + l15;
                bf[tn] = *(const bf16x8*)&Bs[R * 64 + ((gk ^ (R & 7)) * 8)];
            }
#pragma unroll
            for (int tm = 0; tm < 4; ++tm)
#pragma unroll
                for (int tn = 0; tn < 8; ++tn)
                    acc[tm][tn] = __builtin_amdgcn_mfma_f32_16x16x32_bf16(
                        af[tm], bf[tn], acc[tm][tn], 0, 0, 0);
        }
        __syncthreads();
    }

    // epilogue: C layout col = lane&15, row = quad*4 + reg
    float bias[8];
#pragma unroll
    for (int tn = 0; tn < 8; ++tn) {
        int n = n0 + wn * 128 + tn * 16 + l15;
        bias[tn] = baff[n > VOCAB - 1 ? VOCAB - 1 : n];
    }
#pragma unroll
    for (int tm = 0; tm < 4; ++tm) {
        const int mbase = m0 + wm * 64 + tm * 16 + quad * 4;
#pragma unroll
        for (int r = 0; r < 4; ++r) {
            float* orow = out + (size_t)(mbase + r) * VOCAB;
#pragma unroll
            for (int tn = 0; tn < 8; ++tn) {
                int n = n0 + wn * 128 + tn * 16 + l15;
                if (n < VOCAB) orow[n] = acc[tm][tn][r] + bias[tn];
            }
        }
    }
}

extern "C" void kernel_launch(void* const* d_in, const int* in_sizes, int n_in,
                              void* d_out, int out_size, void* d_ws, size_t ws_size,
                              hipStream_t stream) {
    const int* x = (const int*)d_in[0];
    const float* emb = (const float*)d_in[1];
    const float* Wih = (const float*)d_in[2];
    const float* Whh = (const float*)d_in[3];
    const float* bih = (const float*)d_in[4];
    const float* bhh = (const float*)d_in[5];
    const float* Waff = (const float*)d_in[6];
    const float* baff = (const float*)d_in[7];

    float* xin = (float*)d_ws;                                         // 6.55 MB
    uint16_t* hsb = (uint16_t*)((char*)d_ws + (size_t)ROWS * HID * 4); // 3.28 MB
    uint16_t* Wb = hsb + (size_t)ROWS * HID;                           // 5.12 MB
    float* out = (float*)d_out;

    k0_cast<<<(VOCAB * HID) / (256 * 8), 256, 0, stream>>>(Waff, Wb);
    k1_xin<<<ROWS / 8, 256, 0, stream>>>(x, emb, Wih, bih, bhh, xin);
    k2_rnn<<<BATCH, 512, 0, stream>>>(xin, Whh, hsb);
    k3_gemm<<<NTM * NTN, 256, 0, stream>>>(hsb, Wb, baff, out);
}